// Round 9
// baseline (218.461 us; speedup 1.0000x reference)
//
#include <hip/hip_runtime.h>
#include <math.h>

#define BATCH   4
#define S_LEN   2048
#define DMODEL  512
#define NHEADS  8
#define DHEAD   64
#define M_TOT   8192
#define ATT_SCALE 0.04419417382415922f   // 1/sqrt(512)
#define QSCALE (ATT_SCALE * 1.44269504088896f)  // fold log2(e): exp2 in softmax

using short8  = __attribute__((ext_vector_type(8))) short;
using short4v = __attribute__((ext_vector_type(4))) short;
using floatx4 = __attribute__((ext_vector_type(4))) float;

// fp32 -> bf16 RNE
__device__ __forceinline__ ushort f2bf(float f) {
    union { float f; unsigned u; } x; x.f = f;
    unsigned u = x.u + 0x7FFFu + ((x.u >> 16) & 1u);
    return (ushort)(u >> 16);
}
__device__ __forceinline__ unsigned pk2(float a, float b) {
    return (unsigned)f2bf(a) | ((unsigned)f2bf(b) << 16);
}
// fp32x2 -> packed bf16x2, round-half-up — hot-loop use
__device__ __forceinline__ unsigned pkr2(float a, float b) {
    unsigned ua = __float_as_uint(a) + 0x8000u;
    unsigned ub = __float_as_uint(b) + 0x8000u;
    return __builtin_amdgcn_perm(ub, ua, 0x07060302u);
}

// ---------------------------------------------------------------------------
// Preprocess: blocks [0,4096) x fp32->bf16; [4096,4352) W transpose to bf16.
// ---------------------------------------------------------------------------
__global__ __launch_bounds__(256) void prep(
    const float* __restrict__ x,
    const float* __restrict__ Wq, const float* __restrict__ Wk,
    const float* __restrict__ Wv, const float* __restrict__ Wo,
    ushort* __restrict__ xb, ushort* __restrict__ WT)
{
    const int bid = blockIdx.x;
    if (bid < 4096) {
        const int i = (bid * 256 + threadIdx.x) * 4;
        float4 f = *(const float4*)(x + i);
        uint2 o; o.x = pk2(f.x, f.y); o.y = pk2(f.z, f.w);
        *(uint2*)(xb + i) = o;
    } else {
        const int rb = bid - 4096;
        const int p  = rb >> 6;
        const int rem = rb & 63;
        const int n  = (rem >> 5) * 256 + threadIdx.x;
        const int k0 = (rem & 31) * 16;
        const float* W = (p == 0) ? Wq : (p == 1) ? Wk : (p == 2) ? Wv : Wo;
        unsigned u[8];
        #pragma unroll
        for (int j = 0; j < 8; ++j) {
            float a = W[(k0 + 2 * j)     * DMODEL + n];
            float b = W[(k0 + 2 * j + 1) * DMODEL + n];
            u[j] = pk2(a, b);
        }
        ushort* dst = WT + ((size_t)p * DMODEL + n) * DMODEL + k0;
        *(uint4*)dst       = *(uint4*)&u[0];
        *(uint4*)(dst + 8) = *(uint4*)&u[4];
    }
}

// ---------------------------------------------------------------------------
// Kernel 1: fused QKV projection, 128x128 tile, BK=32, VGPR staging +
// register prefetch.  Q pre-scaled by QSCALE; V exits via LDS transpose.
// ---------------------------------------------------------------------------
__global__ __launch_bounds__(256, 4) void qkv_gemm(
    const ushort* __restrict__ xb, const ushort* __restrict__ WT,
    const float* __restrict__ bq, const float* __restrict__ bk, const float* __restrict__ bv,
    ushort* __restrict__ q, ushort* __restrict__ k, ushort* __restrict__ vT)
{
    __shared__ ushort SMEM[128 * 136];   // K-loop A+B (20.5 KB); CT overlay
    ushort (*A)[40] = (ushort(*)[40])SMEM;
    ushort (*B)[40] = (ushort(*)[40])(SMEM + 128 * 40);
    ushort (*CT)[136] = (ushort(*)[136])SMEM;

    const int tid = threadIdx.x;
    const int wv  = tid >> 6, lane = tid & 63, l16 = lane & 15, quad = lane >> 4;
    const int m0  = blockIdx.x * 128;
    const int ng0 = blockIdx.y * 128;
    const int p   = ng0 >> 9;
    const int n0  = ng0 & 511;
    const ushort* Wp  = WT + (size_t)p * DMODEL * DMODEL + (size_t)n0 * DMODEL;
    const float* bias = (p == 0) ? bq : (p == 1) ? bk : bv;
    const float scl   = (p == 0) ? QSCALE : 1.0f;

    const int wm = (wv & 1) * 64, wn = (wv >> 1) * 64;
    floatx4 acc[4][4] = {};
    const int ar = tid >> 1, ac = (tid & 1) * 16;

    uint4 pa0, pa1, pb0, pb1;
    pa0 = *(const uint4*)(xb + (size_t)(m0 + ar) * DMODEL + ac);
    pa1 = *(const uint4*)(xb + (size_t)(m0 + ar) * DMODEL + ac + 8);
    pb0 = *(const uint4*)(Wp + (size_t)ar * DMODEL + ac);
    pb1 = *(const uint4*)(Wp + (size_t)ar * DMODEL + ac + 8);

    for (int k0 = 0; k0 < DMODEL; k0 += 32) {
        *(uint4*)&A[ar][ac] = pa0; *(uint4*)&A[ar][ac + 8] = pa1;
        *(uint4*)&B[ar][ac] = pb0; *(uint4*)&B[ar][ac + 8] = pb1;
        __syncthreads();

        if (k0 + 32 < DMODEL) {
            pa0 = *(const uint4*)(xb + (size_t)(m0 + ar) * DMODEL + k0 + 32 + ac);
            pa1 = *(const uint4*)(xb + (size_t)(m0 + ar) * DMODEL + k0 + 32 + ac + 8);
            pb0 = *(const uint4*)(Wp + (size_t)ar * DMODEL + k0 + 32 + ac);
            pb1 = *(const uint4*)(Wp + (size_t)ar * DMODEL + k0 + 32 + ac + 8);
        }

        short8 af[4], bf[4];
        #pragma unroll
        for (int i = 0; i < 4; ++i) af[i] = *(const short8*)&A[wm + i * 16 + l16][quad * 8];
        #pragma unroll
        for (int c = 0; c < 4; ++c) bf[c] = *(const short8*)&B[wn + c * 16 + l16][quad * 8];
        #pragma unroll
        for (int i = 0; i < 4; ++i)
            #pragma unroll
            for (int c = 0; c < 4; ++c)
                acc[i][c] = __builtin_amdgcn_mfma_f32_16x16x32_bf16(af[i], bf[c], acc[i][c], 0, 0, 0);
        __syncthreads();
    }

    if (p < 2) {
        #pragma unroll
        for (int c = 0; c < 4; ++c) {
            const int n = n0 + wn + c * 16 + l16;
            const float bb = bias[n];
            const int h = n >> 6, dh = n & 63;
            #pragma unroll
            for (int i = 0; i < 4; ++i)
                #pragma unroll
                for (int r = 0; r < 4; ++r) {
                    const int m = m0 + wm + i * 16 + quad * 4 + r;
                    const int b = m >> 11, s = m & 2047;
                    const ushort val = f2bf((acc[i][c][r] + bb) * scl);
                    if (p == 0) q[((size_t)(b * NHEADS + h) * S_LEN + s) * DHEAD + dh] = val;
                    else        k[((size_t)(b * NHEADS + h) * S_LEN + s) * DHEAD + dh] = val;
                }
        }
    } else {
        #pragma unroll
        for (int c = 0; c < 4; ++c) {
            const int n = wn + c * 16 + l16;
            const float bb = bias[n0 + n];
            #pragma unroll
            for (int i = 0; i < 4; ++i) {
                uint2 o;
                o.x = pk2(acc[i][c][0] + bb, acc[i][c][1] + bb);
                o.y = pk2(acc[i][c][2] + bb, acc[i][c][3] + bb);
                *(uint2*)&CT[n][wm + i * 16 + quad * 4] = o;
            }
        }
        __syncthreads();
        const int n  = tid >> 1, mh = (tid & 1) * 64;
        const int gn = n0 + n;
        const int h  = gn >> 6, dh = gn & 63;
        const int b  = m0 >> 11, sb = (m0 & 2047) + mh;
        ushort* dst = vT + ((size_t)(b * NHEADS + h) * DHEAD + dh) * S_LEN + sb;
        #pragma unroll
        for (int j = 0; j < 8; ++j)
            *(uint4*)(dst + j * 8) = *(const uint4*)&CT[n][mh + j * 8];
    }
}

// ---------------------------------------------------------------------------
// Kernel 2: flash attention, S^T = K·Q^T, split-S.  Register-fed PV
// (mfma 16x16x16_1k).  NEW: XCD-aware 1-D grid swizzle (the 16 q-tile
// blocks sharing one (bh,ck) K/V chunk all satisfy bid%8==g%8 -> same XCD,
// chunk lives in that XCD's L2) + distance-2 register prefetch (vmcnt wait
// covers ~2 compute phases > HBM latency).
// ---------------------------------------------------------------------------
__global__ __launch_bounds__(256, 4) void attn(
    const ushort* __restrict__ Q, const ushort* __restrict__ K,
    const ushort* __restrict__ vT,
    float* __restrict__ Opart, float* __restrict__ Lpart, const int KT)
{
    __shared__ ushort Klds[2][64][72];
    __shared__ ushort Vt[2][64][72];

    const int tid = threadIdx.x;
    const int wv  = tid >> 6, lane = tid & 63, l16 = lane & 15, quad = lane >> 4;

    // swizzle decode: bid = (g%8) + 8*q + 128*(g/8), g = bh*2+ck
    const int bid = blockIdx.x;
    const int xg   = bid & 7;
    const int rest = bid >> 3;
    const int qt   = rest & 15;
    const int gh   = rest >> 4;
    const int g    = gh * 8 + xg;
    const int bh   = g >> 1;
    const int ck   = g & 1;
    const int q0   = qt * 128;
    const int kbase = ck * KT;

    const ushort* Qh = Q  + (size_t)bh * S_LEN * DHEAD;
    const ushort* Kh = K  + (size_t)bh * S_LEN * DHEAD;
    const ushort* Vh = vT + (size_t)bh * DHEAD * S_LEN;

    short8 qf[2][2];
    #pragma unroll
    for (int ni = 0; ni < 2; ++ni) {
        const ushort* qrow = Qh + (size_t)(q0 + wv * 32 + ni * 16 + l16) * DHEAD;
        qf[0][ni] = *(const short8*)(qrow + quad * 8);
        qf[1][ni] = *(const short8*)(qrow + 32 + quad * 8);
    }

    floatx4 oacc[4][2] = {};   // O^T: [dh-tile][q-tile]
    float lsum[2] = {0.f, 0.f};

    const int srow = tid >> 2, sc0 = (tid & 3) * 16;
    // distance-2 prefetch: two register sets
    uint4 ka[2], kb[2], va[2], vb[2];
    #pragma unroll
    for (int t = 0; t < 2; ++t) {
        const ushort* Ks = Kh + (size_t)((kbase + t) * 64 + srow) * DHEAD + sc0;
        const ushort* Vs = Vh + (size_t)srow * S_LEN + (kbase + t) * 64 + sc0;
        ka[t] = *(const uint4*)Ks; kb[t] = *(const uint4*)(Ks + 8);
        va[t] = *(const uint4*)Vs; vb[t] = *(const uint4*)(Vs + 8);
    }

    for (int kt = 0; kt < KT; ++kt) {
        const int buf = kt & 1;
        *(uint4*)&Klds[buf][srow][sc0] = ka[buf]; *(uint4*)&Klds[buf][srow][sc0 + 8] = kb[buf];
        *(uint4*)&Vt[buf][srow][sc0]   = va[buf]; *(uint4*)&Vt[buf][srow][sc0 + 8]   = vb[buf];
        __syncthreads();   // sole barrier per iter (dbuf)

        if (kt + 2 < KT) {
            const ushort* Ks = Kh + (size_t)((kbase + kt + 2) * 64 + srow) * DHEAD + sc0;
            const ushort* Vs = Vh + (size_t)srow * S_LEN + (kbase + kt + 2) * 64 + sc0;
            ka[buf] = *(const uint4*)Ks; kb[buf] = *(const uint4*)(Ks + 8);
            va[buf] = *(const uint4*)Vs; vb[buf] = *(const uint4*)(Vs + 8);
        }

        #pragma unroll
        for (int mi = 0; mi < 4; ++mi) {
            floatx4 s0 = {}, s1 = {};
            #pragma unroll
            for (int s = 0; s < 2; ++s) {
                short8 kf = *(const short8*)&Klds[buf][mi * 16 + l16][s * 32 + quad * 8];
                s0 = __builtin_amdgcn_mfma_f32_16x16x32_bf16(kf, qf[s][0], s0, 0, 0, 0);
                s1 = __builtin_amdgcn_mfma_f32_16x16x32_bf16(kf, qf[s][1], s1, 0, 0, 0);
            }
            short4v vfr[4];
            #pragma unroll
            for (int c = 0; c < 4; ++c)
                vfr[c] = *(const short4v*)&Vt[buf][c * 16 + l16][mi * 16 + quad * 4];

            {
                const float p0 = __builtin_amdgcn_exp2f(s0[0]);
                const float p1 = __builtin_amdgcn_exp2f(s0[1]);
                const float p2 = __builtin_amdgcn_exp2f(s0[2]);
                const float p3 = __builtin_amdgcn_exp2f(s0[3]);
                lsum[0] += (p0 + p1) + (p2 + p3);
                uint2 o; o.x = pkr2(p0, p1); o.y = pkr2(p2, p3);
                short4v pf; *(uint2*)&pf = o;
                #pragma unroll
                for (int c = 0; c < 4; ++c)
                    oacc[c][0] = __builtin_amdgcn_mfma_f32_16x16x16bf16_1k(vfr[c], pf, oacc[c][0], 0, 0, 0);
            }
            {
                const float p0 = __builtin_amdgcn_exp2f(s1[0]);
                const float p1 = __builtin_amdgcn_exp2f(s1[1]);
                const float p2 = __builtin_amdgcn_exp2f(s1[2]);
                const float p3 = __builtin_amdgcn_exp2f(s1[3]);
                lsum[1] += (p0 + p1) + (p2 + p3);
                uint2 o; o.x = pkr2(p0, p1); o.y = pkr2(p2, p3);
                short4v pf; *(uint2*)&pf = o;
                #pragma unroll
                for (int c = 0; c < 4; ++c)
                    oacc[c][1] = __builtin_amdgcn_mfma_f32_16x16x16bf16_1k(vfr[c], pf, oacc[c][1], 0, 0, 0);
            }
        }
    }

    float tot[2];
    #pragma unroll
    for (int ni = 0; ni < 2; ++ni) {
        float t = lsum[ni];
        t += __shfl_xor(t, 16, 64);
        t += __shfl_xor(t, 32, 64);
        tot[ni] = t;
    }

    // partials: row = (ck*32+bh)*2048 + qi
    #pragma unroll
    for (int ni = 0; ni < 2; ++ni) {
        const int qi = q0 + wv * 32 + ni * 16 + l16;
        const size_t row = (size_t)(ck * 32 + bh) * S_LEN + qi;
        if (quad == 0) Lpart[row] = tot[ni];
        #pragma unroll
        for (int mi = 0; mi < 4; ++mi) {
            float4 o = { oacc[mi][ni][0], oacc[mi][ni][1],
                         oacc[mi][ni][2], oacc[mi][ni][3] };
            *(float4*)&Opart[row * DHEAD + mi * 16 + quad * 4] = o;
        }
    }
}

// ---------------------------------------------------------------------------
// Kernel 3: output projection fused with split-S combine (round-8 form).
// ---------------------------------------------------------------------------
__global__ __launch_bounds__(256, 4) void out_gemm(
    const float* __restrict__ Opart, const float* __restrict__ Lpart,
    const ushort* __restrict__ WoT, const float* __restrict__ bo,
    float* __restrict__ out)
{
    __shared__ ushort A[64][40];
    __shared__ ushort B[128][40];

    const int tid = threadIdx.x;
    const int wv  = tid >> 6, lane = tid & 63, l16 = lane & 15, quad = lane >> 4;
    const int m0 = blockIdx.x * 64;
    const int n0 = blockIdx.y * 128;

    const int ar = tid >> 2, ac = (tid & 3) * 8;
    const int am = m0 + ar, ab = am >> 11, aq = am & 2047;
    float invl[NHEADS];
    #pragma unroll
    for (int h = 0; h < NHEADS; ++h) {
        const size_t rw = (size_t)(ab * NHEADS + h) * S_LEN + aq;
        invl[h] = 1.f / (Lpart[rw] + Lpart[65536 + rw]);
    }
    const int br = tid >> 1, bc = (tid & 1) * 16;

    floatx4 acc[8] = {};

    for (int k0 = 0; k0 < DMODEL; k0 += 32) {
        const int kk = k0 + ac, h = kk >> 6, dh = kk & 63;
        const float* p0 = Opart + ((size_t)(ab * NHEADS + h) * S_LEN + aq) * DHEAD + dh;
        const float* p1 = p0 + (size_t)65536 * DHEAD;
        float4 a0 = *(const float4*)p0,       a1 = *(const float4*)(p0 + 4);
        float4 c0 = *(const float4*)p1,       c1 = *(const float4*)(p1 + 4);
        const float iv = invl[h];
        uint2 u0, u1;
        u0.x = pk2((a0.x + c0.x) * iv, (a0.y + c0.y) * iv);
        u0.y = pk2((a0.z + c0.z) * iv, (a0.w + c0.w) * iv);
        u1.x = pk2((a1.x + c1.x) * iv, (a1.y + c1.y) * iv);
        u1.y = pk2((a1.z + c1.z) * iv, (a1.w + c1.w) * iv);
        *(uint2*)&A[ar][ac]     = u0;
        *(uint2*)&A[ar][ac + 4] = u1;

        uint4 b0 = *(const uint4*)(WoT + (size_t)(n0 + br) * DMODEL + k0 + bc);
        uint4 b1 = *(const uint4*)(WoT + (size_t)(n0 + br) * DMODEL + k0 + bc + 8);
        *(uint4*)&B[br][bc] = b0; *(uint4*)&B[br][bc + 8] = b1;
        __syncthreads();

        short8 af = *(const short8*)&A[wv * 16 + l16][quad * 8];
        #pragma unroll
        for (int c = 0; c < 8; ++c) {
            short8 bf = *(const short8*)&B[c * 16 + l16][quad * 8];
            acc[c] = __builtin_amdgcn_mfma_f32_16x16x32_bf16(af, bf, acc[c], 0, 0, 0);
        }
        __syncthreads();
    }

    #pragma unroll
    for (int c = 0; c < 8; ++c) {
        const int n = n0 + c * 16 + l16;
        const float bb = bo[n];
        #pragma unroll
        for (int r = 0; r < 4; ++r) {
            const int m = m0 + wv * 16 + quad * 4 + r;
            out[(size_t)m * DMODEL + n] = acc[c][r] + bb;
        }
    }
}

// ---------------------------------------------------------------------------
extern "C" void kernel_launch(void* const* d_in, const int* in_sizes, int n_in,
                              void* d_out, int out_size, void* d_ws, size_t ws_size,
                              hipStream_t stream)
{
    const float* x  = (const float*)d_in[0];
    const float* Wq = (const float*)d_in[1];
    const float* bq = (const float*)d_in[2];
    const float* Wk = (const float*)d_in[3];
    const float* bk = (const float*)d_in[4];
    const float* Wv = (const float*)d_in[5];
    const float* bv = (const float*)d_in[6];
    const float* Wo = (const float*)d_in[7];
    const float* bo = (const float*)d_in[8];
    float* out = (float*)d_out;

    ushort* ws = (ushort*)d_ws;
    const size_t SZ = (size_t)M_TOT * DMODEL;
    ushort* xb  = ws;
    ushort* WT  = ws + SZ;
    ushort* q   = WT + 4 * (size_t)DMODEL * DMODEL;
    ushort* k   = q + SZ;
    ushort* vT  = k + SZ;
    float*  Opart = (float*)(vT + SZ);                        // 2 x 32 x 2048 x 64 fp32
    float*  Lpart = Opart + 2 * (size_t)32 * S_LEN * DHEAD;   // 2 x 32 x 2048 fp32

    prep<<<4096 + 256, 256, 0, stream>>>(x, Wq, Wk, Wv, Wo, xb, WT);

    qkv_gemm<<<dim3(M_TOT / 128, 3 * DMODEL / 128), 256, 0, stream>>>(
        xb, WT, bq, bk, bv, q, k, vT);

    attn<<<1024, 256, 0, stream>>>(q, k, vT, Opart, Lpart, S_LEN / 64 / 2);

    out_gemm<<<dim3(M_TOT / 64, DMODEL / 128), 256, 0, stream>>>(
        Opart, Lpart, WT + 3 * (size_t)DMODEL * DMODEL, bo, out);
}

// Round 10
// 213.952 us; speedup vs baseline: 1.0211x; 1.0211x over previous
//
#include <hip/hip_runtime.h>
#include <math.h>

#define BATCH   4
#define S_LEN   2048
#define DMODEL  512
#define NHEADS  8
#define DHEAD   64
#define M_TOT   8192
#define ATT_SCALE 0.04419417382415922f   // 1/sqrt(512)
#define QSCALE (ATT_SCALE * 1.44269504088896f)  // fold log2(e): exp2 in softmax

using short8  = __attribute__((ext_vector_type(8))) short;
using short4v = __attribute__((ext_vector_type(4))) short;
using floatx4 = __attribute__((ext_vector_type(4))) float;

// fp32 -> bf16 RNE
__device__ __forceinline__ ushort f2bf(float f) {
    union { float f; unsigned u; } x; x.f = f;
    unsigned u = x.u + 0x7FFFu + ((x.u >> 16) & 1u);
    return (ushort)(u >> 16);
}
__device__ __forceinline__ unsigned pk2(float a, float b) {
    return (unsigned)f2bf(a) | ((unsigned)f2bf(b) << 16);
}
// fp32x2 -> packed bf16x2, round-half-up — hot-loop use
__device__ __forceinline__ unsigned pkr2(float a, float b) {
    unsigned ua = __float_as_uint(a) + 0x8000u;
    unsigned ub = __float_as_uint(b) + 0x8000u;
    return __builtin_amdgcn_perm(ub, ua, 0x07060302u);
}

// ---------------------------------------------------------------------------
// Preprocess: blocks [0,4096) x fp32->bf16; [4096,4352) W transpose to bf16.
// ---------------------------------------------------------------------------
__global__ __launch_bounds__(256) void prep(
    const float* __restrict__ x,
    const float* __restrict__ Wq, const float* __restrict__ Wk,
    const float* __restrict__ Wv, const float* __restrict__ Wo,
    ushort* __restrict__ xb, ushort* __restrict__ WT)
{
    const int bid = blockIdx.x;
    if (bid < 4096) {
        const int i = (bid * 256 + threadIdx.x) * 4;
        float4 f = *(const float4*)(x + i);
        uint2 o; o.x = pk2(f.x, f.y); o.y = pk2(f.z, f.w);
        *(uint2*)(xb + i) = o;
    } else {
        const int rb = bid - 4096;
        const int p  = rb >> 6;
        const int rem = rb & 63;
        const int n  = (rem >> 5) * 256 + threadIdx.x;
        const int k0 = (rem & 31) * 16;
        const float* W = (p == 0) ? Wq : (p == 1) ? Wk : (p == 2) ? Wv : Wo;
        unsigned u[8];
        #pragma unroll
        for (int j = 0; j < 8; ++j) {
            float a = W[(k0 + 2 * j)     * DMODEL + n];
            float b = W[(k0 + 2 * j + 1) * DMODEL + n];
            u[j] = pk2(a, b);
        }
        ushort* dst = WT + ((size_t)p * DMODEL + n) * DMODEL + k0;
        *(uint4*)dst       = *(uint4*)&u[0];
        *(uint4*)(dst + 8) = *(uint4*)&u[4];
    }
}

// ---------------------------------------------------------------------------
// Kernel 1: fused QKV projection, 128x128 tile, BK=32, VGPR staging +
// register prefetch.  Q pre-scaled by QSCALE; V exits via LDS transpose.
// ---------------------------------------------------------------------------
__global__ __launch_bounds__(256, 4) void qkv_gemm(
    const ushort* __restrict__ xb, const ushort* __restrict__ WT,
    const float* __restrict__ bq, const float* __restrict__ bk, const float* __restrict__ bv,
    ushort* __restrict__ q, ushort* __restrict__ k, ushort* __restrict__ vT)
{
    __shared__ ushort SMEM[128 * 136];   // K-loop A+B (20.5 KB); CT overlay
    ushort (*A)[40] = (ushort(*)[40])SMEM;
    ushort (*B)[40] = (ushort(*)[40])(SMEM + 128 * 40);
    ushort (*CT)[136] = (ushort(*)[136])SMEM;

    const int tid = threadIdx.x;
    const int wv  = tid >> 6, lane = tid & 63, l16 = lane & 15, quad = lane >> 4;
    const int m0  = blockIdx.x * 128;
    const int ng0 = blockIdx.y * 128;
    const int p   = ng0 >> 9;
    const int n0  = ng0 & 511;
    const ushort* Wp  = WT + (size_t)p * DMODEL * DMODEL + (size_t)n0 * DMODEL;
    const float* bias = (p == 0) ? bq : (p == 1) ? bk : bv;
    const float scl   = (p == 0) ? QSCALE : 1.0f;

    const int wm = (wv & 1) * 64, wn = (wv >> 1) * 64;
    floatx4 acc[4][4] = {};
    const int ar = tid >> 1, ac = (tid & 1) * 16;

    uint4 pa0, pa1, pb0, pb1;
    pa0 = *(const uint4*)(xb + (size_t)(m0 + ar) * DMODEL + ac);
    pa1 = *(const uint4*)(xb + (size_t)(m0 + ar) * DMODEL + ac + 8);
    pb0 = *(const uint4*)(Wp + (size_t)ar * DMODEL + ac);
    pb1 = *(const uint4*)(Wp + (size_t)ar * DMODEL + ac + 8);

    for (int k0 = 0; k0 < DMODEL; k0 += 32) {
        *(uint4*)&A[ar][ac] = pa0; *(uint4*)&A[ar][ac + 8] = pa1;
        *(uint4*)&B[ar][ac] = pb0; *(uint4*)&B[ar][ac + 8] = pb1;
        __syncthreads();

        if (k0 + 32 < DMODEL) {
            pa0 = *(const uint4*)(xb + (size_t)(m0 + ar) * DMODEL + k0 + 32 + ac);
            pa1 = *(const uint4*)(xb + (size_t)(m0 + ar) * DMODEL + k0 + 32 + ac + 8);
            pb0 = *(const uint4*)(Wp + (size_t)ar * DMODEL + k0 + 32 + ac);
            pb1 = *(const uint4*)(Wp + (size_t)ar * DMODEL + k0 + 32 + ac + 8);
        }

        short8 af[4], bf[4];
        #pragma unroll
        for (int i = 0; i < 4; ++i) af[i] = *(const short8*)&A[wm + i * 16 + l16][quad * 8];
        #pragma unroll
        for (int c = 0; c < 4; ++c) bf[c] = *(const short8*)&B[wn + c * 16 + l16][quad * 8];
        #pragma unroll
        for (int i = 0; i < 4; ++i)
            #pragma unroll
            for (int c = 0; c < 4; ++c)
                acc[i][c] = __builtin_amdgcn_mfma_f32_16x16x32_bf16(af[i], bf[c], acc[i][c], 0, 0, 0);
        __syncthreads();
    }

    if (p < 2) {
        #pragma unroll
        for (int c = 0; c < 4; ++c) {
            const int n = n0 + wn + c * 16 + l16;
            const float bb = bias[n];
            const int h = n >> 6, dh = n & 63;
            #pragma unroll
            for (int i = 0; i < 4; ++i)
                #pragma unroll
                for (int r = 0; r < 4; ++r) {
                    const int m = m0 + wm + i * 16 + quad * 4 + r;
                    const int b = m >> 11, s = m & 2047;
                    const ushort val = f2bf((acc[i][c][r] + bb) * scl);
                    if (p == 0) q[((size_t)(b * NHEADS + h) * S_LEN + s) * DHEAD + dh] = val;
                    else        k[((size_t)(b * NHEADS + h) * S_LEN + s) * DHEAD + dh] = val;
                }
        }
    } else {
        #pragma unroll
        for (int c = 0; c < 4; ++c) {
            const int n = wn + c * 16 + l16;
            const float bb = bias[n0 + n];
            #pragma unroll
            for (int i = 0; i < 4; ++i) {
                uint2 o;
                o.x = pk2(acc[i][c][0] + bb, acc[i][c][1] + bb);
                o.y = pk2(acc[i][c][2] + bb, acc[i][c][3] + bb);
                *(uint2*)&CT[n][wm + i * 16 + quad * 4] = o;
            }
        }
        __syncthreads();
        const int n  = tid >> 1, mh = (tid & 1) * 64;
        const int gn = n0 + n;
        const int h  = gn >> 6, dh = gn & 63;
        const int b  = m0 >> 11, sb = (m0 & 2047) + mh;
        ushort* dst = vT + ((size_t)(b * NHEADS + h) * DHEAD + dh) * S_LEN + sb;
        #pragma unroll
        for (int j = 0; j < 8; ++j)
            *(uint4*)(dst + j * 8) = *(const uint4*)&CT[n][mh + j * 8];
    }
}

// ---------------------------------------------------------------------------
// Kernel 2: flash attention, S^T = K·Q^T, split-S, register-fed PV.
// XCD swizzle kept (FETCH 73->59 MB in r9).  Distance-2 prefetch redone with
// SCALAR register sets + manual 2x-unrolled kt loop — no dynamically-indexed
// local arrays (r9's uint4 ka[2] indexed by kt&1 spilled to scratch: 234 MB
// of HBM write traffic, WRITE_SIZE 40->274 MB, VGPR 64->60).
// ---------------------------------------------------------------------------
__global__ __launch_bounds__(256, 4) void attn(
    const ushort* __restrict__ Q, const ushort* __restrict__ K,
    const ushort* __restrict__ vT,
    float* __restrict__ Opart, float* __restrict__ Lpart, const int KT)
{
    __shared__ ushort Klds[2][64][72];
    __shared__ ushort Vt[2][64][72];

    const int tid = threadIdx.x;
    const int wv  = tid >> 6, lane = tid & 63, l16 = lane & 15, quad = lane >> 4;

    // swizzle decode: bid = (g%8) + 8*qt + 128*(g/8), g = bh*2+ck
    const int bid = blockIdx.x;
    const int xg   = bid & 7;
    const int rest = bid >> 3;
    const int qt   = rest & 15;
    const int gh   = rest >> 4;
    const int g    = gh * 8 + xg;
    const int bh   = g >> 1;
    const int ck   = g & 1;
    const int q0   = qt * 128;
    const int kbase = ck * KT;

    const ushort* Qh = Q  + (size_t)bh * S_LEN * DHEAD;
    const ushort* Kh = K  + (size_t)bh * S_LEN * DHEAD;
    const ushort* Vh = vT + (size_t)bh * DHEAD * S_LEN;

    short8 qf[2][2];
    #pragma unroll
    for (int ni = 0; ni < 2; ++ni) {
        const ushort* qrow = Qh + (size_t)(q0 + wv * 32 + ni * 16 + l16) * DHEAD;
        qf[0][ni] = *(const short8*)(qrow + quad * 8);
        qf[1][ni] = *(const short8*)(qrow + 32 + quad * 8);
    }

    floatx4 oacc[4][2] = {};   // O^T: [dh-tile][q-tile]
    float lsum[2] = {0.f, 0.f};

    const int srow = tid >> 2, sc0 = (tid & 3) * 16;
    const ushort* Kb = Kh + (size_t)srow * DHEAD + sc0;     // + kt*64*DHEAD
    const ushort* Vb = Vh + (size_t)srow * S_LEN + sc0;     // + kt*64

    // scalar prefetch sets: set0 = even tiles, set1 = odd tiles
    uint4 ka0, kb0, va0, vb0, ka1, kb1, va1, vb1;
    {
        const ushort* Ks = Kb + (size_t)(kbase + 0) * 64 * DHEAD;
        const ushort* Vs = Vb + (kbase + 0) * 64;
        ka0 = *(const uint4*)Ks; kb0 = *(const uint4*)(Ks + 8);
        va0 = *(const uint4*)Vs; vb0 = *(const uint4*)(Vs + 8);
        Ks += 64 * DHEAD; Vs += 64;
        ka1 = *(const uint4*)Ks; kb1 = *(const uint4*)(Ks + 8);
        va1 = *(const uint4*)Vs; vb1 = *(const uint4*)(Vs + 8);
    }

    // compute body over one LDS buffer (buf is a compile-time constant)
    auto compute = [&](const ushort (*Kl)[72], const ushort (*Vl)[72]) {
        #pragma unroll
        for (int mi = 0; mi < 4; ++mi) {
            floatx4 s0 = {}, s1 = {};
            #pragma unroll
            for (int s = 0; s < 2; ++s) {
                short8 kf = *(const short8*)&Kl[mi * 16 + l16][s * 32 + quad * 8];
                s0 = __builtin_amdgcn_mfma_f32_16x16x32_bf16(kf, qf[s][0], s0, 0, 0, 0);
                s1 = __builtin_amdgcn_mfma_f32_16x16x32_bf16(kf, qf[s][1], s1, 0, 0, 0);
            }
            short4v vfr[4];
            #pragma unroll
            for (int c = 0; c < 4; ++c)
                vfr[c] = *(const short4v*)&Vl[c * 16 + l16][mi * 16 + quad * 4];
            {
                const float p0 = __builtin_amdgcn_exp2f(s0[0]);
                const float p1 = __builtin_amdgcn_exp2f(s0[1]);
                const float p2 = __builtin_amdgcn_exp2f(s0[2]);
                const float p3 = __builtin_amdgcn_exp2f(s0[3]);
                lsum[0] += (p0 + p1) + (p2 + p3);
                uint2 o; o.x = pkr2(p0, p1); o.y = pkr2(p2, p3);
                short4v pf; *(uint2*)&pf = o;
                #pragma unroll
                for (int c = 0; c < 4; ++c)
                    oacc[c][0] = __builtin_amdgcn_mfma_f32_16x16x16bf16_1k(vfr[c], pf, oacc[c][0], 0, 0, 0);
            }
            {
                const float p0 = __builtin_amdgcn_exp2f(s1[0]);
                const float p1 = __builtin_amdgcn_exp2f(s1[1]);
                const float p2 = __builtin_amdgcn_exp2f(s1[2]);
                const float p3 = __builtin_amdgcn_exp2f(s1[3]);
                lsum[1] += (p0 + p1) + (p2 + p3);
                uint2 o; o.x = pkr2(p0, p1); o.y = pkr2(p2, p3);
                short4v pf; *(uint2*)&pf = o;
                #pragma unroll
                for (int c = 0; c < 4; ++c)
                    oacc[c][1] = __builtin_amdgcn_mfma_f32_16x16x16bf16_1k(vfr[c], pf, oacc[c][1], 0, 0, 0);
            }
        }
    };

    for (int kt = 0; kt < KT; kt += 2) {
        // even iter: buf 0 <- set0; refill set0 with tile kt+2
        *(uint4*)&Klds[0][srow][sc0] = ka0; *(uint4*)&Klds[0][srow][sc0 + 8] = kb0;
        *(uint4*)&Vt[0][srow][sc0]   = va0; *(uint4*)&Vt[0][srow][sc0 + 8]   = vb0;
        __syncthreads();
        if (kt + 2 < KT) {
            const ushort* Ks = Kb + (size_t)(kbase + kt + 2) * 64 * DHEAD;
            const ushort* Vs = Vb + (kbase + kt + 2) * 64;
            ka0 = *(const uint4*)Ks; kb0 = *(const uint4*)(Ks + 8);
            va0 = *(const uint4*)Vs; vb0 = *(const uint4*)(Vs + 8);
        }
        compute(Klds[0], Vt[0]);

        // odd iter: buf 1 <- set1; refill set1 with tile kt+3
        *(uint4*)&Klds[1][srow][sc0] = ka1; *(uint4*)&Klds[1][srow][sc0 + 8] = kb1;
        *(uint4*)&Vt[1][srow][sc0]   = va1; *(uint4*)&Vt[1][srow][sc0 + 8]   = vb1;
        __syncthreads();
        if (kt + 3 < KT) {
            const ushort* Ks = Kb + (size_t)(kbase + kt + 3) * 64 * DHEAD;
            const ushort* Vs = Vb + (kbase + kt + 3) * 64;
            ka1 = *(const uint4*)Ks; kb1 = *(const uint4*)(Ks + 8);
            va1 = *(const uint4*)Vs; vb1 = *(const uint4*)(Vs + 8);
        }
        compute(Klds[1], Vt[1]);
    }

    float tot[2];
    #pragma unroll
    for (int ni = 0; ni < 2; ++ni) {
        float t = lsum[ni];
        t += __shfl_xor(t, 16, 64);
        t += __shfl_xor(t, 32, 64);
        tot[ni] = t;
    }

    // partials: row = (ck*32+bh)*2048 + qi
    #pragma unroll
    for (int ni = 0; ni < 2; ++ni) {
        const int qi = q0 + wv * 32 + ni * 16 + l16;
        const size_t row = (size_t)(ck * 32 + bh) * S_LEN + qi;
        if (quad == 0) Lpart[row] = tot[ni];
        #pragma unroll
        for (int mi = 0; mi < 4; ++mi) {
            float4 o = { oacc[mi][ni][0], oacc[mi][ni][1],
                         oacc[mi][ni][2], oacc[mi][ni][3] };
            *(float4*)&Opart[row * DHEAD + mi * 16 + quad * 4] = o;
        }
    }
}

// ---------------------------------------------------------------------------
// Kernel 3: output projection fused with split-S combine (round-8 form).
// ---------------------------------------------------------------------------
__global__ __launch_bounds__(256, 4) void out_gemm(
    const float* __restrict__ Opart, const float* __restrict__ Lpart,
    const ushort* __restrict__ WoT, const float* __restrict__ bo,
    float* __restrict__ out)
{
    __shared__ ushort A[64][40];
    __shared__ ushort B[128][40];

    const int tid = threadIdx.x;
    const int wv  = tid >> 6, lane = tid & 63, l16 = lane & 15, quad = lane >> 4;
    const int m0 = blockIdx.x * 64;
    const int n0 = blockIdx.y * 128;

    const int ar = tid >> 2, ac = (tid & 3) * 8;
    const int am = m0 + ar, ab = am >> 11, aq = am & 2047;
    float invl[NHEADS];
    #pragma unroll
    for (int h = 0; h < NHEADS; ++h) {
        const size_t rw = (size_t)(ab * NHEADS + h) * S_LEN + aq;
        invl[h] = 1.f / (Lpart[rw] + Lpart[65536 + rw]);
    }
    const int br = tid >> 1, bc = (tid & 1) * 16;

    floatx4 acc[8] = {};

    for (int k0 = 0; k0 < DMODEL; k0 += 32) {
        const int kk = k0 + ac, h = kk >> 6, dh = kk & 63;
        const float* p0 = Opart + ((size_t)(ab * NHEADS + h) * S_LEN + aq) * DHEAD + dh;
        const float* p1 = p0 + (size_t)65536 * DHEAD;
        float4 a0 = *(const float4*)p0,       a1 = *(const float4*)(p0 + 4);
        float4 c0 = *(const float4*)p1,       c1 = *(const float4*)(p1 + 4);
        const float iv = invl[h];
        uint2 u0, u1;
        u0.x = pk2((a0.x + c0.x) * iv, (a0.y + c0.y) * iv);
        u0.y = pk2((a0.z + c0.z) * iv, (a0.w + c0.w) * iv);
        u1.x = pk2((a1.x + c1.x) * iv, (a1.y + c1.y) * iv);
        u1.y = pk2((a1.z + c1.z) * iv, (a1.w + c1.w) * iv);
        *(uint2*)&A[ar][ac]     = u0;
        *(uint2*)&A[ar][ac + 4] = u1;

        uint4 b0 = *(const uint4*)(WoT + (size_t)(n0 + br) * DMODEL + k0 + bc);
        uint4 b1 = *(const uint4*)(WoT + (size_t)(n0 + br) * DMODEL + k0 + bc + 8);
        *(uint4*)&B[br][bc] = b0; *(uint4*)&B[br][bc + 8] = b1;
        __syncthreads();

        short8 af = *(const short8*)&A[wv * 16 + l16][quad * 8];
        #pragma unroll
        for (int c = 0; c < 8; ++c) {
            short8 bf = *(const short8*)&B[c * 16 + l16][quad * 8];
            acc[c] = __builtin_amdgcn_mfma_f32_16x16x32_bf16(af, bf, acc[c], 0, 0, 0);
        }
        __syncthreads();
    }

    #pragma unroll
    for (int c = 0; c < 8; ++c) {
        const int n = n0 + c * 16 + l16;
        const float bb = bo[n];
        #pragma unroll
        for (int r = 0; r < 4; ++r) {
            const int m = m0 + wv * 16 + quad * 4 + r;
            out[(size_t)m * DMODEL + n] = acc[c][r] + bb;
        }
    }
}

// ---------------------------------------------------------------------------
extern "C" void kernel_launch(void* const* d_in, const int* in_sizes, int n_in,
                              void* d_out, int out_size, void* d_ws, size_t ws_size,
                              hipStream_t stream)
{
    const float* x  = (const float*)d_in[0];
    const float* Wq = (const float*)d_in[1];
    const float* bq = (const float*)d_in[2];
    const float* Wk = (const float*)d_in[3];
    const float* bk = (const float*)d_in[4];
    const float* Wv = (const float*)d_in[5];
    const float* bv = (const float*)d_in[6];
    const float* Wo = (const float*)d_in[7];
    const float* bo = (const float*)d_in[8];
    float* out = (float*)d_out;

    ushort* ws = (ushort*)d_ws;
    const size_t SZ = (size_t)M_TOT * DMODEL;
    ushort* xb  = ws;
    ushort* WT  = ws + SZ;
    ushort* q   = WT + 4 * (size_t)DMODEL * DMODEL;
    ushort* k   = q + SZ;
    ushort* vT  = k + SZ;
    float*  Opart = (float*)(vT + SZ);                        // 2 x 32 x 2048 x 64 fp32
    float*  Lpart = Opart + 2 * (size_t)32 * S_LEN * DHEAD;   // 2 x 32 x 2048 fp32

    prep<<<4096 + 256, 256, 0, stream>>>(x, Wq, Wk, Wv, Wo, xb, WT);

    qkv_gemm<<<dim3(M_TOT / 128, 3 * DMODEL / 128), 256, 0, stream>>>(
        xb, WT, bq, bk, bv, q, k, vT);

    attn<<<1024, 256, 0, stream>>>(q, k, vT, Opart, Lpart, S_LEN / 64 / 2);

    out_gemm<<<dim3(M_TOT / 64, DMODEL / 128), 256, 0, stream>>>(
        Opart, Lpart, WT + 3 * (size_t)DMODEL * DMODEL, bo, out);
}

// Round 11
// 179.117 us; speedup vs baseline: 1.2197x; 1.1945x over previous
//
#include <hip/hip_runtime.h>
#include <math.h>

#define BATCH   4
#define S_LEN   2048
#define DMODEL  512
#define NHEADS  8
#define DHEAD   64
#define M_TOT   8192
#define ATT_SCALE 0.04419417382415922f   // 1/sqrt(512)
#define QSCALE (ATT_SCALE * 1.44269504088896f)  // fold log2(e): exp2 in softmax

using short8  = __attribute__((ext_vector_type(8))) short;
using short4v = __attribute__((ext_vector_type(4))) short;
using floatx4 = __attribute__((ext_vector_type(4))) float;

// fp32 -> bf16 RNE
__device__ __forceinline__ ushort f2bf(float f) {
    union { float f; unsigned u; } x; x.f = f;
    unsigned u = x.u + 0x7FFFu + ((x.u >> 16) & 1u);
    return (ushort)(u >> 16);
}
__device__ __forceinline__ unsigned pk2(float a, float b) {
    return (unsigned)f2bf(a) | ((unsigned)f2bf(b) << 16);
}
// fp32x2 -> packed bf16x2, round-half-up — hot-loop use
__device__ __forceinline__ unsigned pkr2(float a, float b) {
    unsigned ua = __float_as_uint(a) + 0x8000u;
    unsigned ub = __float_as_uint(b) + 0x8000u;
    return __builtin_amdgcn_perm(ub, ua, 0x07060302u);
}

// ---------------------------------------------------------------------------
// Preprocess: W transpose only (x is now consumed fp32 directly by qkv_gemm).
// WT[p][n][k] = W_p[k][n] bf16; 256 blocks.
// ---------------------------------------------------------------------------
__global__ __launch_bounds__(256) void prep(
    const float* __restrict__ Wq, const float* __restrict__ Wk,
    const float* __restrict__ Wv, const float* __restrict__ Wo,
    ushort* __restrict__ WT)
{
    const int rb = blockIdx.x;
    const int p  = rb >> 6;
    const int rem = rb & 63;
    const int n  = (rem >> 5) * 256 + threadIdx.x;
    const int k0 = (rem & 31) * 16;
    const float* W = (p == 0) ? Wq : (p == 1) ? Wk : (p == 2) ? Wv : Wo;
    unsigned u[8];
    #pragma unroll
    for (int j = 0; j < 8; ++j) {
        float a = W[(k0 + 2 * j)     * DMODEL + n];
        float b = W[(k0 + 2 * j + 1) * DMODEL + n];
        u[j] = pk2(a, b);
    }
    ushort* dst = WT + ((size_t)p * DMODEL + n) * DMODEL + k0;
    *(uint4*)dst       = *(uint4*)&u[0];
    *(uint4*)(dst + 8) = *(uint4*)&u[4];
}

// ---------------------------------------------------------------------------
// Kernel 1: fused QKV projection, 128x128 tile, BK=32, VGPR staging +
// register prefetch.  A read DIRECTLY from fp32 x (packed to bf16 at
// prefetch time -> live state stays 2 uint4, same as round 8).
// Q pre-scaled by QSCALE; V exits via LDS transpose.
// ---------------------------------------------------------------------------
__global__ __launch_bounds__(256, 4) void qkv_gemm(
    const float* __restrict__ x, const ushort* __restrict__ WT,
    const float* __restrict__ bq, const float* __restrict__ bk, const float* __restrict__ bv,
    ushort* __restrict__ q, ushort* __restrict__ k, ushort* __restrict__ vT)
{
    __shared__ ushort SMEM[128 * 136];   // K-loop A+B (20.5 KB); CT overlay
    ushort (*A)[40] = (ushort(*)[40])SMEM;
    ushort (*B)[40] = (ushort(*)[40])(SMEM + 128 * 40);
    ushort (*CT)[136] = (ushort(*)[136])SMEM;

    const int tid = threadIdx.x;
    const int wv  = tid >> 6, lane = tid & 63, l16 = lane & 15, quad = lane >> 4;
    const int m0  = blockIdx.x * 128;
    const int ng0 = blockIdx.y * 128;
    const int p   = ng0 >> 9;
    const int n0  = ng0 & 511;
    const ushort* Wp  = WT + (size_t)p * DMODEL * DMODEL + (size_t)n0 * DMODEL;
    const float* bias = (p == 0) ? bq : (p == 1) ? bk : bv;
    const float scl   = (p == 0) ? QSCALE : 1.0f;

    const int wm = (wv & 1) * 64, wn = (wv >> 1) * 64;
    floatx4 acc[4][4] = {};
    const int ar = tid >> 1, ac = (tid & 1) * 16;
    const float* xrow = x + (size_t)(m0 + ar) * DMODEL;

    // prefetch tile 0: A loaded fp32, packed immediately to 2 uint4
    uint4 pa0, pa1, pb0, pb1;
    {
        float4 f0 = *(const float4*)(xrow + ac);
        float4 f1 = *(const float4*)(xrow + ac + 4);
        float4 f2 = *(const float4*)(xrow + ac + 8);
        float4 f3 = *(const float4*)(xrow + ac + 12);
        pa0.x = pk2(f0.x, f0.y); pa0.y = pk2(f0.z, f0.w);
        pa0.z = pk2(f1.x, f1.y); pa0.w = pk2(f1.z, f1.w);
        pa1.x = pk2(f2.x, f2.y); pa1.y = pk2(f2.z, f2.w);
        pa1.z = pk2(f3.x, f3.y); pa1.w = pk2(f3.z, f3.w);
    }
    pb0 = *(const uint4*)(Wp + (size_t)ar * DMODEL + ac);
    pb1 = *(const uint4*)(Wp + (size_t)ar * DMODEL + ac + 8);

    for (int k0 = 0; k0 < DMODEL; k0 += 32) {
        *(uint4*)&A[ar][ac] = pa0; *(uint4*)&A[ar][ac + 8] = pa1;
        *(uint4*)&B[ar][ac] = pb0; *(uint4*)&B[ar][ac + 8] = pb1;
        __syncthreads();

        if (k0 + 32 < DMODEL) {
            float4 f0 = *(const float4*)(xrow + k0 + 32 + ac);
            float4 f1 = *(const float4*)(xrow + k0 + 32 + ac + 4);
            float4 f2 = *(const float4*)(xrow + k0 + 32 + ac + 8);
            float4 f3 = *(const float4*)(xrow + k0 + 32 + ac + 12);
            pa0.x = pk2(f0.x, f0.y); pa0.y = pk2(f0.z, f0.w);
            pa0.z = pk2(f1.x, f1.y); pa0.w = pk2(f1.z, f1.w);
            pa1.x = pk2(f2.x, f2.y); pa1.y = pk2(f2.z, f2.w);
            pa1.z = pk2(f3.x, f3.y); pa1.w = pk2(f3.z, f3.w);
            pb0 = *(const uint4*)(Wp + (size_t)ar * DMODEL + k0 + 32 + ac);
            pb1 = *(const uint4*)(Wp + (size_t)ar * DMODEL + k0 + 32 + ac + 8);
        }

        short8 af[4], bf[4];
        #pragma unroll
        for (int i = 0; i < 4; ++i) af[i] = *(const short8*)&A[wm + i * 16 + l16][quad * 8];
        #pragma unroll
        for (int c = 0; c < 4; ++c) bf[c] = *(const short8*)&B[wn + c * 16 + l16][quad * 8];
        #pragma unroll
        for (int i = 0; i < 4; ++i)
            #pragma unroll
            for (int c = 0; c < 4; ++c)
                acc[i][c] = __builtin_amdgcn_mfma_f32_16x16x32_bf16(af[i], bf[c], acc[i][c], 0, 0, 0);
        __syncthreads();
    }

    if (p < 2) {
        #pragma unroll
        for (int c = 0; c < 4; ++c) {
            const int n = n0 + wn + c * 16 + l16;
            const float bb = bias[n];
            const int h = n >> 6, dh = n & 63;
            #pragma unroll
            for (int i = 0; i < 4; ++i)
                #pragma unroll
                for (int r = 0; r < 4; ++r) {
                    const int m = m0 + wm + i * 16 + quad * 4 + r;
                    const int b = m >> 11, s = m & 2047;
                    const ushort val = f2bf((acc[i][c][r] + bb) * scl);
                    if (p == 0) q[((size_t)(b * NHEADS + h) * S_LEN + s) * DHEAD + dh] = val;
                    else        k[((size_t)(b * NHEADS + h) * S_LEN + s) * DHEAD + dh] = val;
                }
        }
    } else {
        #pragma unroll
        for (int c = 0; c < 4; ++c) {
            const int n = wn + c * 16 + l16;
            const float bb = bias[n0 + n];
            #pragma unroll
            for (int i = 0; i < 4; ++i) {
                uint2 o;
                o.x = pk2(acc[i][c][0] + bb, acc[i][c][1] + bb);
                o.y = pk2(acc[i][c][2] + bb, acc[i][c][3] + bb);
                *(uint2*)&CT[n][wm + i * 16 + quad * 4] = o;
            }
        }
        __syncthreads();
        const int n  = tid >> 1, mh = (tid & 1) * 64;
        const int gn = n0 + n;
        const int h  = gn >> 6, dh = gn & 63;
        const int b  = m0 >> 11, sb = (m0 & 2047) + mh;
        ushort* dst = vT + ((size_t)(b * NHEADS + h) * DHEAD + dh) * S_LEN + sb;
        #pragma unroll
        for (int j = 0; j < 8; ++j)
            *(uint4*)(dst + j * 8) = *(const uint4*)&CT[n][mh + j * 8];
    }
}

// ---------------------------------------------------------------------------
// Kernel 2: flash attention — round-8 body VERBATIM (dist-1 prefetch, plain
// scalars, no lambda/arrays: r8 measured VGPR=64, WRITE=40MB, no spill)
// + XCD-aware 1-D swizzle grid (r9-measured FETCH 73->59 MB).
// ---------------------------------------------------------------------------
__global__ __launch_bounds__(256, 4) void attn(
    const ushort* __restrict__ Q, const ushort* __restrict__ K,
    const ushort* __restrict__ vT,
    float* __restrict__ Opart, float* __restrict__ Lpart, const int KT)
{
    __shared__ ushort Klds[2][64][72];
    __shared__ ushort Vt[2][64][72];

    const int tid = threadIdx.x;
    const int wv  = tid >> 6, lane = tid & 63, l16 = lane & 15, quad = lane >> 4;

    // swizzle decode: bid = (g%8) + 8*qt + 128*(g/8), g = bh*2+ck
    const int bid = blockIdx.x;
    const int xg   = bid & 7;
    const int rest = bid >> 3;
    const int qt   = rest & 15;
    const int gh   = rest >> 4;
    const int g    = gh * 8 + xg;
    const int bh   = g >> 1;
    const int ck   = g & 1;
    const int q0   = qt * 128;
    const int kbase = ck * KT;

    const ushort* Qh = Q  + (size_t)bh * S_LEN * DHEAD;
    const ushort* Kh = K  + (size_t)bh * S_LEN * DHEAD;
    const ushort* Vh = vT + (size_t)bh * DHEAD * S_LEN;

    short8 qf[2][2];
    #pragma unroll
    for (int ni = 0; ni < 2; ++ni) {
        const ushort* qrow = Qh + (size_t)(q0 + wv * 32 + ni * 16 + l16) * DHEAD;
        qf[0][ni] = *(const short8*)(qrow + quad * 8);
        qf[1][ni] = *(const short8*)(qrow + 32 + quad * 8);
    }

    floatx4 oacc[4][2] = {};   // O^T: [dh-tile][q-tile]
    float lsum[2] = {0.f, 0.f};

    const int srow = tid >> 2, sc0 = (tid & 3) * 16;
    uint4 ka, kb, va, vb;
    {
        const ushort* Ks = Kh + (size_t)(kbase * 64 + srow) * DHEAD + sc0;
        const ushort* Vs = Vh + (size_t)srow * S_LEN + kbase * 64 + sc0;
        ka = *(const uint4*)Ks; kb = *(const uint4*)(Ks + 8);
        va = *(const uint4*)Vs; vb = *(const uint4*)(Vs + 8);
    }

    for (int kt = 0; kt < KT; ++kt) {
        const int buf = kt & 1;
        *(uint4*)&Klds[buf][srow][sc0] = ka; *(uint4*)&Klds[buf][srow][sc0 + 8] = kb;
        *(uint4*)&Vt[buf][srow][sc0]   = va; *(uint4*)&Vt[buf][srow][sc0 + 8]   = vb;
        __syncthreads();   // sole barrier: dbuf makes the tail barrier unnecessary

        if (kt + 1 < KT) {
            const ushort* Ks = Kh + (size_t)((kbase + kt + 1) * 64 + srow) * DHEAD + sc0;
            const ushort* Vs = Vh + (size_t)srow * S_LEN + (kbase + kt + 1) * 64 + sc0;
            ka = *(const uint4*)Ks; kb = *(const uint4*)(Ks + 8);
            va = *(const uint4*)Vs; vb = *(const uint4*)(Vs + 8);
        }

        #pragma unroll
        for (int mi = 0; mi < 4; ++mi) {
            // S^T for this 16-key block: lane = (key quad*4+r, q l16)
            floatx4 s0 = {}, s1 = {};
            #pragma unroll
            for (int s = 0; s < 2; ++s) {
                short8 kf = *(const short8*)&Klds[buf][mi * 16 + l16][s * 32 + quad * 8];
                s0 = __builtin_amdgcn_mfma_f32_16x16x32_bf16(kf, qf[s][0], s0, 0, 0, 0);
                s1 = __builtin_amdgcn_mfma_f32_16x16x32_bf16(kf, qf[s][1], s1, 0, 0, 0);
            }
            // V^T A-fragments for the K=16 PV MFMA: A[m=dh=c*16+l16][k=quad*4+j]
            short4v vfr[4];
            #pragma unroll
            for (int c = 0; c < 4; ++c)
                vfr[c] = *(const short4v*)&Vt[buf][c * 16 + l16][mi * 16 + quad * 4];

            // ni = 0
            {
                const float p0 = __builtin_amdgcn_exp2f(s0[0]);
                const float p1 = __builtin_amdgcn_exp2f(s0[1]);
                const float p2 = __builtin_amdgcn_exp2f(s0[2]);
                const float p3 = __builtin_amdgcn_exp2f(s0[3]);
                lsum[0] += (p0 + p1) + (p2 + p3);
                uint2 o; o.x = pkr2(p0, p1); o.y = pkr2(p2, p3);
                short4v pf; *(uint2*)&pf = o;   // keys quad*4+{0..3}, q=l16
                #pragma unroll
                for (int c = 0; c < 4; ++c)
                    oacc[c][0] = __builtin_amdgcn_mfma_f32_16x16x16bf16_1k(vfr[c], pf, oacc[c][0], 0, 0, 0);
            }
            // ni = 1
            {
                const float p0 = __builtin_amdgcn_exp2f(s1[0]);
                const float p1 = __builtin_amdgcn_exp2f(s1[1]);
                const float p2 = __builtin_amdgcn_exp2f(s1[2]);
                const float p3 = __builtin_amdgcn_exp2f(s1[3]);
                lsum[1] += (p0 + p1) + (p2 + p3);
                uint2 o; o.x = pkr2(p0, p1); o.y = pkr2(p2, p3);
                short4v pf; *(uint2*)&pf = o;
                #pragma unroll
                for (int c = 0; c < 4; ++c)
                    oacc[c][1] = __builtin_amdgcn_mfma_f32_16x16x16bf16_1k(vfr[c], pf, oacc[c][1], 0, 0, 0);
            }
        }
    }

    float tot[2];
    #pragma unroll
    for (int ni = 0; ni < 2; ++ni) {
        float t = lsum[ni];
        t += __shfl_xor(t, 16, 64);
        t += __shfl_xor(t, 32, 64);
        tot[ni] = t;
    }

    // partials: row = (ck*32+bh)*2048 + qi
    #pragma unroll
    for (int ni = 0; ni < 2; ++ni) {
        const int qi = q0 + wv * 32 + ni * 16 + l16;
        const size_t row = (size_t)(ck * 32 + bh) * S_LEN + qi;
        if (quad == 0) Lpart[row] = tot[ni];
        #pragma unroll
        for (int mi = 0; mi < 4; ++mi) {
            float4 o = { oacc[mi][ni][0], oacc[mi][ni][1],
                         oacc[mi][ni][2], oacc[mi][ni][3] };
            *(float4*)&Opart[row * DHEAD + mi * 16 + quad * 4] = o;
        }
    }
}

// ---------------------------------------------------------------------------
// Kernel 3: output projection fused with split-S combine (round-8 form).
// ---------------------------------------------------------------------------
__global__ __launch_bounds__(256, 4) void out_gemm(
    const float* __restrict__ Opart, const float* __restrict__ Lpart,
    const ushort* __restrict__ WoT, const float* __restrict__ bo,
    float* __restrict__ out)
{
    __shared__ ushort A[64][40];
    __shared__ ushort B[128][40];

    const int tid = threadIdx.x;
    const int wv  = tid >> 6, lane = tid & 63, l16 = lane & 15, quad = lane >> 4;
    const int m0 = blockIdx.x * 64;
    const int n0 = blockIdx.y * 128;

    const int ar = tid >> 2, ac = (tid & 3) * 8;
    const int am = m0 + ar, ab = am >> 11, aq = am & 2047;
    float invl[NHEADS];
    #pragma unroll
    for (int h = 0; h < NHEADS; ++h) {
        const size_t rw = (size_t)(ab * NHEADS + h) * S_LEN + aq;
        invl[h] = 1.f / (Lpart[rw] + Lpart[65536 + rw]);
    }
    const int br = tid >> 1, bc = (tid & 1) * 16;

    floatx4 acc[8] = {};

    for (int k0 = 0; k0 < DMODEL; k0 += 32) {
        const int kk = k0 + ac, h = kk >> 6, dh = kk & 63;
        const float* p0 = Opart + ((size_t)(ab * NHEADS + h) * S_LEN + aq) * DHEAD + dh;
        const float* p1 = p0 + (size_t)65536 * DHEAD;
        float4 a0 = *(const float4*)p0,       a1 = *(const float4*)(p0 + 4);
        float4 c0 = *(const float4*)p1,       c1 = *(const float4*)(p1 + 4);
        const float iv = invl[h];
        uint2 u0, u1;
        u0.x = pk2((a0.x + c0.x) * iv, (a0.y + c0.y) * iv);
        u0.y = pk2((a0.z + c0.z) * iv, (a0.w + c0.w) * iv);
        u1.x = pk2((a1.x + c1.x) * iv, (a1.y + c1.y) * iv);
        u1.y = pk2((a1.z + c1.z) * iv, (a1.w + c1.w) * iv);
        *(uint2*)&A[ar][ac]     = u0;
        *(uint2*)&A[ar][ac + 4] = u1;

        uint4 b0 = *(const uint4*)(WoT + (size_t)(n0 + br) * DMODEL + k0 + bc);
        uint4 b1 = *(const uint4*)(WoT + (size_t)(n0 + br) * DMODEL + k0 + bc + 8);
        *(uint4*)&B[br][bc] = b0; *(uint4*)&B[br][bc + 8] = b1;
        __syncthreads();

        short8 af = *(const short8*)&A[wv * 16 + l16][quad * 8];
        #pragma unroll
        for (int c = 0; c < 8; ++c) {
            short8 bf = *(const short8*)&B[c * 16 + l16][quad * 8];
            acc[c] = __builtin_amdgcn_mfma_f32_16x16x32_bf16(af, bf, acc[c], 0, 0, 0);
        }
        __syncthreads();
    }

    #pragma unroll
    for (int c = 0; c < 8; ++c) {
        const int n = n0 + c * 16 + l16;
        const float bb = bo[n];
        #pragma unroll
        for (int r = 0; r < 4; ++r) {
            const int m = m0 + wv * 16 + quad * 4 + r;
            out[(size_t)m * DMODEL + n] = acc[c][r] + bb;
        }
    }
}

// ---------------------------------------------------------------------------
extern "C" void kernel_launch(void* const* d_in, const int* in_sizes, int n_in,
                              void* d_out, int out_size, void* d_ws, size_t ws_size,
                              hipStream_t stream)
{
    const float* x  = (const float*)d_in[0];
    const float* Wq = (const float*)d_in[1];
    const float* bq = (const float*)d_in[2];
    const float* Wk = (const float*)d_in[3];
    const float* bk = (const float*)d_in[4];
    const float* Wv = (const float*)d_in[5];
    const float* bv = (const float*)d_in[6];
    const float* Wo = (const float*)d_in[7];
    const float* bo = (const float*)d_in[8];
    float* out = (float*)d_out;

    ushort* ws = (ushort*)d_ws;
    const size_t SZ = (size_t)M_TOT * DMODEL;
    ushort* WT  = ws;
    ushort* q   = WT + 4 * (size_t)DMODEL * DMODEL;
    ushort* k   = q + SZ;
    ushort* vT  = k + SZ;
    float*  Opart = (float*)(vT + SZ);                        // 2 x 32 x 2048 x 64 fp32
    float*  Lpart = Opart + 2 * (size_t)32 * S_LEN * DHEAD;   // 2 x 32 x 2048 fp32

    prep<<<256, 256, 0, stream>>>(Wq, Wk, Wv, Wo, WT);

    qkv_gemm<<<dim3(M_TOT / 128, 3 * DMODEL / 128), 256, 0, stream>>>(
        x, WT, bq, bk, bv, q, k, vT);

    attn<<<1024, 256, 0, stream>>>(q, k, vT, Opart, Lpart, S_LEN / 64 / 2);

    out_gemm<<<dim3(M_TOT / 64, DMODEL / 128), 256, 0, stream>>>(
        Opart, Lpart, WT + 3 * (size_t)DMODEL * DMODEL, bo, out);
}